// Round 15
// baseline (32.005 us; speedup 1.0000x reference)
//
#include <hip/hip_runtime.h>
#include <math.h>

// Problem constants (reference: B,D,E,H = 4,128,512,512)
#define BATCH 4
#define DDIM  128
#define EDIM  512
#define HDIM  512

// c = 2*log2(e): P=exp2(c*dec_t), Q=exp2(c*enc_t) so e^{2(dec+enc)} = P*Q
#define TANH_SCALE 2.8853900817779268f

typedef short short8v __attribute__((ext_vector_type(8)));
typedef float f32x4   __attribute__((ext_vector_type(4)));
typedef float f32x2   __attribute__((ext_vector_type(2)));

#define EXP2F(x) __builtin_amdgcn_exp2f(x)
#define RCPF(x)  __builtin_amdgcn_rcpf(x)

// fp32 -> bf16 bits, round-to-nearest-even (GEMM input staging only)
static __device__ inline unsigned short f2bf(float f) {
    unsigned u = __float_as_uint(f);
    return (unsigned short)((u + 0x7FFFu + ((u >> 16) & 1u)) >> 16);
}
// pack two fp32 -> one u32 {bf16(f1):bf16(f0)}
static __device__ inline unsigned pack_bf2(float f0, float f1) {
    unsigned u0 = __float_as_uint(f0), u1 = __float_as_uint(f1);
    u0 += 0x7FFFu + ((u0 >> 16) & 1u);
    u1 += 0x7FFFu + ((u1 >> 16) & 1u);
    return __builtin_amdgcn_perm(u1, u0, 0x07060302u);
}

// ---------------------------------------------------------------------------
// bf16 MFMA GEMM pair (NT), 2-phase pipeline — structure UNCHANGED from R13;
// epilogue now stores f32 (no f2bf pack) so attn needs no unpack.
//   blocks 0..63   : P[b,d,h] = exp2(c * sum_k xdec[b,d,k]*W2[h,k])
//   blocks 64..319 : Q[b,h,e] = exp2(c * sum_k W1[h,k]*xenc[b,e,k])
// ---------------------------------------------------------------------------
__global__ __launch_bounds__(256)
void gemm_both(const float* __restrict__ xdec, const float* __restrict__ W2,
               const float* __restrict__ xenc, const float* __restrict__ W1,
               float* __restrict__ P, float* __restrict__ Q) {
    __shared__ unsigned short As[2][64][40];   // 10 KB (dbuf, 80B rows)
    __shared__ unsigned short Bs[2][64][40];   // 10 KB

    const int id = blockIdx.x;
    const float *Ab, *Bb;
    float* Cb;
    int m0, n0;
    if (id < 64) {                 // dec: 4b x 2m(d) x 8n(h)
        int b = id >> 4, r = id & 15;
        m0 = (r >> 3) * 64; n0 = (r & 7) * 64;
        Ab = xdec + (long)b * DDIM * HDIM;
        Bb = W2;
        Cb = P + (long)b * DDIM * HDIM;
    } else {                       // enc: 4b x 8m(h) x 8n(e)
        int t2 = id - 64;
        int b = t2 >> 6, r = t2 & 63;
        m0 = (r >> 3) * 64; n0 = (r & 7) * 64;
        Ab = W1;
        Bb = xenc + (long)b * EDIM * HDIM;
        Cb = Q + (long)b * HDIM * EDIM;
    }

    const int t    = threadIdx.x;
    const int srow = t >> 2;            // 0..63: staged row
    const int skq  = (t & 3) << 3;      // 0,8,16,24: k-offset (8 elems)

    const int wid = t >> 6, wm = wid >> 1, wn = wid & 1;
    const int l   = t & 63, lr = l & 15, c16 = l >> 4;

    f32x4 acc[2][2] = {};

    const float* ap = Ab + (long)(m0 + srow) * HDIM + skq;
    const float* bp = Bb + (long)(n0 + srow) * HDIM + skq;

    float4 a0 = *(const float4*)ap, a1 = *(const float4*)(ap + 4);
    float4 b0 = *(const float4*)bp, b1 = *(const float4*)(bp + 4);

    int cur = 0;
    for (int k0 = 0; k0 < HDIM; k0 += 32) {
        uint4 apk, bpk;
        apk.x = pack_bf2(a0.x, a0.y); apk.y = pack_bf2(a0.z, a0.w);
        apk.z = pack_bf2(a1.x, a1.y); apk.w = pack_bf2(a1.z, a1.w);
        bpk.x = pack_bf2(b0.x, b0.y); bpk.y = pack_bf2(b0.z, b0.w);
        bpk.z = pack_bf2(b1.x, b1.y); bpk.w = pack_bf2(b1.z, b1.w);
        *(uint4*)&As[cur][srow][skq] = apk;
        *(uint4*)&Bs[cur][srow][skq] = bpk;

        if (k0 + 32 < HDIM) {
            ap += 32; bp += 32;
            a0 = *(const float4*)ap; a1 = *(const float4*)(ap + 4);
            b0 = *(const float4*)bp; b1 = *(const float4*)(bp + 4);
        }

        asm volatile("s_waitcnt lgkmcnt(0)" ::: "memory");
        __builtin_amdgcn_s_barrier();
        __builtin_amdgcn_sched_barrier(0);

        short8v af[2], bf[2];
        #pragma unroll
        for (int fm = 0; fm < 2; ++fm)
            af[fm] = *(const short8v*)&As[cur][wm * 32 + fm * 16 + lr][c16 * 8];
        #pragma unroll
        for (int fn = 0; fn < 2; ++fn)
            bf[fn] = *(const short8v*)&Bs[cur][wn * 32 + fn * 16 + lr][c16 * 8];
        #pragma unroll
        for (int fm = 0; fm < 2; ++fm)
            #pragma unroll
            for (int fn = 0; fn < 2; ++fn)
                acc[fm][fn] = __builtin_amdgcn_mfma_f32_16x16x32_bf16(
                    af[fm], bf[fn], acc[fm][fn], 0, 0, 0);
        cur ^= 1;
    }

    const int crow = c16 << 2;
    #pragma unroll
    for (int fm = 0; fm < 2; ++fm)
        #pragma unroll
        for (int fn = 0; fn < 2; ++fn)
            #pragma unroll
            for (int r = 0; r < 4; ++r) {
                int rr = m0 + wm * 32 + fm * 16 + crow + r;
                int cc = n0 + wn * 32 + fn * 16 + lr;
                Cb[(long)rr * 512 + cc] = EXP2F(TANH_SCALE * acc[fm][fn][r]);
            }
}

// ---------------------------------------------------------------------------
// MERGED attn + log_softmax — R13 structure + math, f32 P/Q (NO unpack:
// float4 loads feed PAIR_SET as adjacent-VGPR f32x2 pairs directly).
// 256 blocks (1/CU), 1024 threads = 128 e-quads(4e) x 8 h-groups(64h).
// ---------------------------------------------------------------------------
__global__ __launch_bounds__(1024)
void attn_lsm(const float* __restrict__ P,             // (B,D,H) f32 exp2
              const float* __restrict__ Q,             // (B,H,E) f32 exp2
              const unsigned char* __restrict__ mask,  // (B,E)
              const float* __restrict__ vw,            // (H)
              float* __restrict__ out) {               // (B,D,E)
    const int g    = blockIdx.x;            // 0..255
    const int xcd  = g & 7;
    const int b    = xcd & 3;
    const int dp   = (g >> 3) + ((xcd >> 2) << 5);     // 0..63
    const int pair = b * 64 + dp;           // 0..255
    const int bd0  = pair * 2;
    const int t    = threadIdx.x;           // 0..1023
    const int eq   = t & 127;               // e-quad (4 e's each)
    const int hg   = t >> 7;                // h-subgroup 0..7 (64 h each)

    __shared__ f32x2 combo2[256][3];        // per h-pair {P0pr,P1pr,(a,b)} 6KB
    __shared__ float lds[8][128][9];        // padded reduce buffer (36.9KB)
    __shared__ float red[16];

    if (t < 256) {
        int h = t * 2;
        f32x2 p0, p1, vv;
        p0.x = P[bd0 * HDIM + h];       p0.y = P[bd0 * HDIM + h + 1];
        p1.x = P[(bd0 + 1) * HDIM + h]; p1.y = P[(bd0 + 1) * HDIM + h + 1];
        vv.x = -2.0f * vw[h];           vv.y = -2.0f * vw[h + 1];
        combo2[t][0] = p0; combo2[t][1] = p1; combo2[t][2] = vv;
    }
    __syncthreads();

    const float* qb = Q + b * HDIM * EDIM + (hg * 64) * EDIM + eq * 4;
    float a00 = 0.f, a01 = 0.f, a02 = 0.f, a03 = 0.f;
    float a10 = 0.f, a11 = 0.f, a12 = 0.f, a13 = 0.f;
    f32x2 ones; ones.x = 1.0f; ones.y = 1.0f;

    // one "set": e-pair x d-row x (h0,h1) -> 5 pk + 2 rcp + 2 fma
#define PAIR_SET(Pp, q0p, q1p, VV, accA, accB)                                  \
    {                                                                           \
        f32x2 xp, yp, den, tt, num;                                             \
        asm("v_pk_fma_f32 %0, %1, %2, %3 op_sel_hi:[0,1,1]"                     \
            : "=v"(xp) : "v"(Pp), "v"(q0p), "v"(ones));                         \
        asm("v_pk_fma_f32 %0, %1, %2, %3 op_sel:[1,0,0] op_sel_hi:[1,1,1]"      \
            : "=v"(yp) : "v"(Pp), "v"(q1p), "v"(ones));                         \
        asm("v_pk_mul_f32 %0, %1, %2" : "=v"(den) : "v"(xp), "v"(yp));          \
        asm("v_pk_mul_f32 %0, %1, %2 op_sel:[1,0] op_sel_hi:[1,1]"              \
            : "=v"(tt) : "v"(VV), "v"(xp));                                     \
        asm("v_pk_fma_f32 %0, %1, %2, %3 op_sel_hi:[0,1,1]"                     \
            : "=v"(num) : "v"(VV), "v"(yp), "v"(tt));                           \
        accA = fmaf(num.x, RCPF(den.x), accA);                                  \
        accB = fmaf(num.y, RCPF(den.y), accB);                                  \
    }

    #pragma unroll 4
    for (int ii = 0; ii < 32; ++ii) {       // 32 h-pairs = 64 h
        float4 r0 = *(const float4*)(qb + (size_t)(2 * ii) * EDIM);
        float4 r1 = *(const float4*)(qb + (size_t)(2 * ii + 1) * EDIM);
        f32x2 P0 = combo2[hg * 32 + ii][0];
        f32x2 P1 = combo2[hg * 32 + ii][1];
        f32x2 VV = combo2[hg * 32 + ii][2];
        f32x2 qA0, qB0, qA1, qB1;           // (e0,e1) and (e2,e3) per h
        qA0.x = r0.x; qA0.y = r0.y;
        qB0.x = r0.z; qB0.y = r0.w;
        qA1.x = r1.x; qA1.y = r1.y;
        qB1.x = r1.z; qB1.y = r1.w;

        PAIR_SET(P0, qA0, qA1, VV, a00, a01);
        PAIR_SET(P0, qB0, qB1, VV, a02, a03);
        PAIR_SET(P1, qA0, qA1, VV, a10, a11);
        PAIR_SET(P1, qB0, qB1, VV, a12, a13);
    }
#undef PAIR_SET

    float* myl = &lds[hg][eq][0];
    myl[0] = a00; myl[1] = a01; myl[2] = a02; myl[3] = a03;
    myl[4] = a10; myl[5] = a11; myl[6] = a12; myl[7] = a13;
    __syncthreads();

    // cross-subgroup reduce: thread t owns output position t = d*512 + e
    const int d = t >> 9, e = t & 511;
    const int j = d * 4 + (e & 3), eqi = e >> 2;
    float acc = ((lds[0][eqi][j] + lds[1][eqi][j]) +
                 (lds[2][eqi][j] + lds[3][eqi][j])) +
                ((lds[4][eqi][j] + lds[5][eqi][j]) +
                 (lds[6][eqi][j] + lds[7][eqi][j]));

    const bool mk = mask[b * EDIM + e];
    float val = mk ? -INFINITY : acc;

    // --- masked log_softmax: waves 0..7 = d0, waves 8..15 = d1 ---
    const int wv = t >> 6, lid = t & 63, dg8 = d * 8;

    float m = val;
    #pragma unroll
    for (int o = 32; o >= 1; o >>= 1) m = fmaxf(m, __shfl_xor(m, o));
    if (lid == 0) red[wv] = m;
    __syncthreads();
    m = red[dg8];
    #pragma unroll
    for (int i = 1; i < 8; ++i) m = fmaxf(m, red[dg8 + i]);
    __syncthreads();

    float s = __expf(val - m);
    #pragma unroll
    for (int o = 32; o >= 1; o >>= 1) s += __shfl_xor(s, o);
    if (lid == 0) red[wv] = s;
    __syncthreads();
    float tot = 0.f;
    #pragma unroll
    for (int i = 0; i < 8; ++i) tot += red[dg8 + i];

    out[(long)(bd0 + d) * EDIM + e] = val - m - __logf(tot);
}

// ---------------------------------------------------------------------------
extern "C" void kernel_launch(void* const* d_in, const int* in_sizes, int n_in,
                              void* d_out, int out_size, void* d_ws, size_t ws_size,
                              hipStream_t stream) {
    const float*         xdec = (const float*)d_in[0];         // (B,D,H)
    const float*         xenc = (const float*)d_in[1];         // (B,E,H)
    const unsigned char* mask = (const unsigned char*)d_in[2]; // (B,E)
    const float*         W1   = (const float*)d_in[3];         // (H,H)
    const float*         W2   = (const float*)d_in[4];         // (H,H)
    const float*         vw   = (const float*)d_in[5];         // (H)
    float*               out  = (float*)d_out;                 // (B,D,E)

    float* P = (float*)d_ws;                                   // 262144 f32 (1 MB)
    float* Q = P + 262144;                                     // 1048576 f32 (4 MB)

    gemm_both<<<320, 256, 0, stream>>>(xdec, W2, xenc, W1, P, Q);
    attn_lsm<<<256, 1024, 0, stream>>>(P, Q, mask, vw, out);
}

// Round 16
// 31.360 us; speedup vs baseline: 1.0206x; 1.0206x over previous
//
#include <hip/hip_runtime.h>
#include <math.h>

// Problem constants (reference: B,D,E,H = 4,128,512,512)
#define BATCH 4
#define DDIM  128
#define EDIM  512
#define HDIM  512

// c = 2*log2(e): P=exp2(c*dec_t), Q=exp2(c*enc_t) so e^{2(dec+enc)} = P*Q
#define TANH_SCALE 2.8853900817779268f

typedef short short8v __attribute__((ext_vector_type(8)));
typedef float f32x4   __attribute__((ext_vector_type(4)));
typedef float f32x2   __attribute__((ext_vector_type(2)));

#define EXP2F(x) __builtin_amdgcn_exp2f(x)
#define RCPF(x)  __builtin_amdgcn_rcpf(x)

// fp32 -> bf16 bits, round-to-nearest-even
static __device__ inline unsigned short f2bf(float f) {
    unsigned u = __float_as_uint(f);
    return (unsigned short)((u + 0x7FFFu + ((u >> 16) & 1u)) >> 16);
}
// pack two fp32 -> one u32 {bf16(f1):bf16(f0)}
static __device__ inline unsigned pack_bf2(float f0, float f1) {
    unsigned u0 = __float_as_uint(f0), u1 = __float_as_uint(f1);
    u0 += 0x7FFFu + ((u0 >> 16) & 1u);
    u1 += 0x7FFFu + ((u1 >> 16) & 1u);
    return __builtin_amdgcn_perm(u1, u0, 0x07060302u);
}
// bf16 bits -> fp32
static __device__ inline float bf2f(unsigned short h) {
    return __uint_as_float(((unsigned)h) << 16);
}

// ---------------------------------------------------------------------------
// bf16 MFMA GEMM pair (NT), 2-phase pipeline, 64x128 tiles -> 160 blocks
// (single dispatch round, no tail; R13 ran 320 blocks = 1.25 rounds).
// 256 threads = 4 waves (2m x 2n), wave tile 32x64 = 2x4 frags of 16x16x32,
// 8 MFMA/wave/K-step. Pipeline identical to R13: dbuf LDS, next K-step's
// global loads issued before the barrier, raw s_barrier + lgkmcnt(0) only
// (vmcnt stays outstanding across the barrier).
//   blocks 0..31   : P[b,d,h] = exp2(c * sum_k xdec[b,d,k]*W2[h,k])
//   blocks 32..159 : Q[b,h,e] = exp2(c * sum_k W1[h,k]*xenc[b,e,k])
// ---------------------------------------------------------------------------
__global__ __launch_bounds__(256)
void gemm_both(const float* __restrict__ xdec, const float* __restrict__ W2,
               const float* __restrict__ xenc, const float* __restrict__ W1,
               unsigned short* __restrict__ P, unsigned short* __restrict__ Q) {
    __shared__ unsigned short As[2][64][40];    // 10 KB (dbuf, 80B rows)
    __shared__ unsigned short Bs[2][128][40];   // 20 KB

    const int id = blockIdx.x;
    const float *Ab, *Bb;
    unsigned short* Cb;
    int m0, n0;
    if (id < 32) {                 // dec: 4b x 2m(d) x 4n(h)
        int b = id >> 3, r = id & 7;
        m0 = (r >> 2) * 64; n0 = (r & 3) * 128;
        Ab = xdec + (long)b * DDIM * HDIM;
        Bb = W2;
        Cb = P + (long)b * DDIM * HDIM;
    } else {                       // enc: 4b x 8m(h) x 4n(e)
        int t2 = id - 32;
        int b = t2 >> 5, r = t2 & 31;
        m0 = (r >> 2) * 64; n0 = (r & 3) * 128;
        Ab = W1;
        Bb = xenc + (long)b * EDIM * HDIM;
        Cb = Q + (long)b * HDIM * EDIM;
    }

    const int t    = threadIdx.x;
    const int arow = t >> 2, ak = (t & 3) << 3;   // A: 8 elems of one row
    const int brow = t >> 1, bk = (t & 1) << 4;   // B: 16 elems of one row

    const int wid = t >> 6, wm = wid >> 1, wn = wid & 1;
    const int l   = t & 63, lr = l & 15, c16 = l >> 4;

    f32x4 acc[2][4] = {};

    const float* ap = Ab + (long)(m0 + arow) * HDIM + ak;
    const float* bp = Bb + (long)(n0 + brow) * HDIM + bk;

    // prologue: load K-step 0
    float4 a0 = *(const float4*)ap, a1 = *(const float4*)(ap + 4);
    float4 b0 = *(const float4*)bp, b1 = *(const float4*)(bp + 4);
    float4 b2 = *(const float4*)(bp + 8), b3 = *(const float4*)(bp + 12);

    int cur = 0;
    for (int k0 = 0; k0 < HDIM; k0 += 32) {
        // ---- pack current regs -> LDS[cur] ----
        uint4 apk, bpk0, bpk1;
        apk.x  = pack_bf2(a0.x, a0.y); apk.y  = pack_bf2(a0.z, a0.w);
        apk.z  = pack_bf2(a1.x, a1.y); apk.w  = pack_bf2(a1.z, a1.w);
        bpk0.x = pack_bf2(b0.x, b0.y); bpk0.y = pack_bf2(b0.z, b0.w);
        bpk0.z = pack_bf2(b1.x, b1.y); bpk0.w = pack_bf2(b1.z, b1.w);
        bpk1.x = pack_bf2(b2.x, b2.y); bpk1.y = pack_bf2(b2.z, b2.w);
        bpk1.z = pack_bf2(b3.x, b3.y); bpk1.w = pack_bf2(b3.z, b3.w);
        *(uint4*)&As[cur][arow][ak]     = apk;
        *(uint4*)&Bs[cur][brow][bk]     = bpk0;
        *(uint4*)&Bs[cur][brow][bk + 8] = bpk1;

        // ---- issue next K-step's loads (stay in flight across barrier) ----
        if (k0 + 32 < HDIM) {
            ap += 32; bp += 32;
            a0 = *(const float4*)ap; a1 = *(const float4*)(ap + 4);
            b0 = *(const float4*)bp; b1 = *(const float4*)(bp + 4);
            b2 = *(const float4*)(bp + 8); b3 = *(const float4*)(bp + 12);
        }

        // ---- barrier: ds ops drained, vmcnt NOT drained ----
        asm volatile("s_waitcnt lgkmcnt(0)" ::: "memory");
        __builtin_amdgcn_s_barrier();
        __builtin_amdgcn_sched_barrier(0);

        // ---- fragments + MFMA from LDS[cur] ----
        short8v af[2], bf[4];
        #pragma unroll
        for (int fm = 0; fm < 2; ++fm)
            af[fm] = *(const short8v*)&As[cur][wm * 32 + fm * 16 + lr][c16 * 8];
        #pragma unroll
        for (int fn = 0; fn < 4; ++fn)
            bf[fn] = *(const short8v*)&Bs[cur][wn * 64 + fn * 16 + lr][c16 * 8];
        #pragma unroll
        for (int fm = 0; fm < 2; ++fm)
            #pragma unroll
            for (int fn = 0; fn < 4; ++fn)
                acc[fm][fn] = __builtin_amdgcn_mfma_f32_16x16x32_bf16(
                    af[fm], bf[fn], acc[fm][fn], 0, 0, 0);
        cur ^= 1;
    }

    // epilogue: D[row=c16*4+r][col=lr] -> bf16(exp2(c*acc))
    const int crow = c16 << 2;
    #pragma unroll
    for (int fm = 0; fm < 2; ++fm)
        #pragma unroll
        for (int fn = 0; fn < 4; ++fn)
            #pragma unroll
            for (int r = 0; r < 4; ++r) {
                int rr = m0 + wm * 32 + fm * 16 + crow + r;
                int cc = n0 + wn * 64 + fn * 16 + lr;
                Cb[(long)rr * 512 + cc] = f2bf(EXP2F(TANH_SCALE * acc[fm][fn][r]));
            }
}

// ---------------------------------------------------------------------------
// MERGED attn + log_softmax — byte-identical to R13 (best measured: 30.7).
// 256 blocks (1/CU), 1024 threads = 128 e-quads(4e) x 8 h-groups(64h).
// ---------------------------------------------------------------------------
__global__ __launch_bounds__(1024)
void attn_lsm(const unsigned short* __restrict__ P,    // (B,D,H) bf16 exp2
              const unsigned short* __restrict__ Q,    // (B,H,E) bf16 exp2
              const unsigned char* __restrict__ mask,  // (B,E)
              const float* __restrict__ vw,            // (H)
              float* __restrict__ out) {               // (B,D,E)
    const int g    = blockIdx.x;            // 0..255
    const int xcd  = g & 7;
    const int b    = xcd & 3;
    const int dp   = (g >> 3) + ((xcd >> 2) << 5);     // 0..63
    const int pair = b * 64 + dp;           // 0..255
    const int bd0  = pair * 2;
    const int t    = threadIdx.x;           // 0..1023
    const int eq   = t & 127;               // e-quad (4 e's each)
    const int hg   = t >> 7;                // h-subgroup 0..7 (64 h each)

    __shared__ f32x2 combo2[256][3];        // per h-pair {P0pr,P1pr,(a,b)} 6KB
    __shared__ float lds[8][128][9];        // padded reduce buffer (36.9KB)
    __shared__ float red[16];

    if (t < 256) {
        int h = t * 2;
        f32x2 p0, p1, vv;
        p0.x = bf2f(P[bd0 * HDIM + h]);       p0.y = bf2f(P[bd0 * HDIM + h + 1]);
        p1.x = bf2f(P[(bd0 + 1) * HDIM + h]); p1.y = bf2f(P[(bd0 + 1) * HDIM + h + 1]);
        vv.x = -2.0f * vw[h];                 vv.y = -2.0f * vw[h + 1];
        combo2[t][0] = p0; combo2[t][1] = p1; combo2[t][2] = vv;
    }
    __syncthreads();

    const unsigned short* qb = Q + b * HDIM * EDIM + (hg * 64) * EDIM + eq * 4;
    float a00 = 0.f, a01 = 0.f, a02 = 0.f, a03 = 0.f;
    float a10 = 0.f, a11 = 0.f, a12 = 0.f, a13 = 0.f;
    f32x2 ones; ones.x = 1.0f; ones.y = 1.0f;

    // one "set": e-pair x d-row x (h0,h1) -> 5 pk + 2 rcp + 2 fma
#define PAIR_SET(Pp, q0p, q1p, VV, accA, accB)                                  \
    {                                                                           \
        f32x2 xp, yp, den, tt, num;                                             \
        asm("v_pk_fma_f32 %0, %1, %2, %3 op_sel_hi:[0,1,1]"                     \
            : "=v"(xp) : "v"(Pp), "v"(q0p), "v"(ones));                         \
        asm("v_pk_fma_f32 %0, %1, %2, %3 op_sel:[1,0,0] op_sel_hi:[1,1,1]"      \
            : "=v"(yp) : "v"(Pp), "v"(q1p), "v"(ones));                         \
        asm("v_pk_mul_f32 %0, %1, %2" : "=v"(den) : "v"(xp), "v"(yp));          \
        asm("v_pk_mul_f32 %0, %1, %2 op_sel:[1,0] op_sel_hi:[1,1]"              \
            : "=v"(tt) : "v"(VV), "v"(xp));                                     \
        asm("v_pk_fma_f32 %0, %1, %2, %3 op_sel_hi:[0,1,1]"                     \
            : "=v"(num) : "v"(VV), "v"(yp), "v"(tt));                           \
        accA = fmaf(num.x, RCPF(den.x), accA);                                  \
        accB = fmaf(num.y, RCPF(den.y), accB);                                  \
    }

    #pragma unroll 4
    for (int ii = 0; ii < 32; ++ii) {       // 32 h-pairs = 64 h
        uint2 qv0 = *(const uint2*)(qb + (size_t)(2 * ii) * EDIM);
        uint2 qv1 = *(const uint2*)(qb + (size_t)(2 * ii + 1) * EDIM);
        f32x2 P0 = combo2[hg * 32 + ii][0];
        f32x2 P1 = combo2[hg * 32 + ii][1];
        f32x2 VV = combo2[hg * 32 + ii][2];
        f32x2 qA0, qB0, qA1, qB1;           // (e0,e1) and (e2,e3) per h
        qA0.x = __uint_as_float(qv0.x << 16);
        qA0.y = __uint_as_float(qv0.x & 0xffff0000u);
        qB0.x = __uint_as_float(qv0.y << 16);
        qB0.y = __uint_as_float(qv0.y & 0xffff0000u);
        qA1.x = __uint_as_float(qv1.x << 16);
        qA1.y = __uint_as_float(qv1.x & 0xffff0000u);
        qB1.x = __uint_as_float(qv1.y << 16);
        qB1.y = __uint_as_float(qv1.y & 0xffff0000u);

        PAIR_SET(P0, qA0, qA1, VV, a00, a01);
        PAIR_SET(P0, qB0, qB1, VV, a02, a03);
        PAIR_SET(P1, qA0, qA1, VV, a10, a11);
        PAIR_SET(P1, qB0, qB1, VV, a12, a13);
    }
#undef PAIR_SET

    float* myl = &lds[hg][eq][0];
    myl[0] = a00; myl[1] = a01; myl[2] = a02; myl[3] = a03;
    myl[4] = a10; myl[5] = a11; myl[6] = a12; myl[7] = a13;
    __syncthreads();

    // cross-subgroup reduce: thread t owns output position t = d*512 + e
    const int d = t >> 9, e = t & 511;
    const int j = d * 4 + (e & 3), eqi = e >> 2;
    float acc = ((lds[0][eqi][j] + lds[1][eqi][j]) +
                 (lds[2][eqi][j] + lds[3][eqi][j])) +
                ((lds[4][eqi][j] + lds[5][eqi][j]) +
                 (lds[6][eqi][j] + lds[7][eqi][j]));

    const bool mk = mask[b * EDIM + e];
    float val = mk ? -INFINITY : acc;

    // --- masked log_softmax: waves 0..7 = d0, waves 8..15 = d1 ---
    const int wv = t >> 6, lid = t & 63, dg8 = d * 8;

    float m = val;
    #pragma unroll
    for (int o = 32; o >= 1; o >>= 1) m = fmaxf(m, __shfl_xor(m, o));
    if (lid == 0) red[wv] = m;
    __syncthreads();
    m = red[dg8];
    #pragma unroll
    for (int i = 1; i < 8; ++i) m = fmaxf(m, red[dg8 + i]);
    __syncthreads();

    float s = __expf(val - m);
    #pragma unroll
    for (int o = 32; o >= 1; o >>= 1) s += __shfl_xor(s, o);
    if (lid == 0) red[wv] = s;
    __syncthreads();
    float tot = 0.f;
    #pragma unroll
    for (int i = 0; i < 8; ++i) tot += red[dg8 + i];

    out[(long)(bd0 + d) * EDIM + e] = val - m - __logf(tot);
}

// ---------------------------------------------------------------------------
extern "C" void kernel_launch(void* const* d_in, const int* in_sizes, int n_in,
                              void* d_out, int out_size, void* d_ws, size_t ws_size,
                              hipStream_t stream) {
    const float*         xdec = (const float*)d_in[0];         // (B,D,H)
    const float*         xenc = (const float*)d_in[1];         // (B,E,H)
    const unsigned char* mask = (const unsigned char*)d_in[2]; // (B,E)
    const float*         W1   = (const float*)d_in[3];         // (H,H)
    const float*         W2   = (const float*)d_in[4];         // (H,H)
    const float*         vw   = (const float*)d_in[5];         // (H)
    float*               out  = (float*)d_out;                 // (B,D,E)

    unsigned short* P = (unsigned short*)d_ws;                 // 262144 bf16 (512 KB)
    unsigned short* Q = P + 262144;                            // 1048576 bf16 (2 MB)

    gemm_both<<<160, 256, 0, stream>>>(xdec, W2, xenc, W1, P, Q);
    attn_lsm<<<256, 1024, 0, stream>>>(P, Q, mask, vw, out);
}

// Round 17
// 30.500 us; speedup vs baseline: 1.0494x; 1.0282x over previous
//
#include <hip/hip_runtime.h>
#include <math.h>

// Problem constants (reference: B,D,E,H = 4,128,512,512)
#define BATCH 4
#define DDIM  128
#define EDIM  512
#define HDIM  512

// c = 2*log2(e): P=exp2(c*dec_t), Q=exp2(c*enc_t) so e^{2(dec+enc)} = P*Q
#define TANH_SCALE 2.8853900817779268f

typedef short short8v __attribute__((ext_vector_type(8)));
typedef float f32x4   __attribute__((ext_vector_type(4)));
typedef float f32x2   __attribute__((ext_vector_type(2)));

#define EXP2F(x) __builtin_amdgcn_exp2f(x)
#define RCPF(x)  __builtin_amdgcn_rcpf(x)

// fp32 -> bf16 bits, round-to-nearest-even
static __device__ inline unsigned short f2bf(float f) {
    unsigned u = __float_as_uint(f);
    return (unsigned short)((u + 0x7FFFu + ((u >> 16) & 1u)) >> 16);
}
// pack two fp32 -> one u32 {bf16(f1):bf16(f0)}
static __device__ inline unsigned pack_bf2(float f0, float f1) {
    unsigned u0 = __float_as_uint(f0), u1 = __float_as_uint(f1);
    u0 += 0x7FFFu + ((u0 >> 16) & 1u);
    u1 += 0x7FFFu + ((u1 >> 16) & 1u);
    return __builtin_amdgcn_perm(u1, u0, 0x07060302u);
}
// bf16 bits -> fp32
static __device__ inline float bf2f(unsigned short h) {
    return __uint_as_float(((unsigned)h) << 16);
}

// ---------------------------------------------------------------------------
// bf16 MFMA GEMM pair (NT), 2-phase pipeline — R13 version (best measured).
// 64x64 tile, BK=32, 256 threads = 4 waves (2m x 2n), wave tile 32x32.
// Double-buffered LDS; next K-step's global loads issued BEFORE the barrier;
// raw s_barrier preceded by lgkmcnt(0) ONLY (vmcnt stays outstanding across
// the barrier -> HBM/L2 latency hides under MFMA).
//   blocks 0..63   : P[b,d,h] = exp2(c * sum_k xdec[b,d,k]*W2[h,k])
//   blocks 64..319 : Q[b,h,e] = exp2(c * sum_k W1[h,k]*xenc[b,e,k])
// ---------------------------------------------------------------------------
__global__ __launch_bounds__(256)
void gemm_both(const float* __restrict__ xdec, const float* __restrict__ W2,
               const float* __restrict__ xenc, const float* __restrict__ W1,
               unsigned short* __restrict__ P, unsigned short* __restrict__ Q) {
    __shared__ unsigned short As[2][64][40];   // 10 KB (dbuf, 80B rows)
    __shared__ unsigned short Bs[2][64][40];   // 10 KB

    const int id = blockIdx.x;
    const float *Ab, *Bb;
    unsigned short* Cb;
    int m0, n0;
    if (id < 64) {                 // dec: 4b x 2m(d) x 8n(h)
        int b = id >> 4, r = id & 15;
        m0 = (r >> 3) * 64; n0 = (r & 7) * 64;
        Ab = xdec + (long)b * DDIM * HDIM;
        Bb = W2;
        Cb = P + (long)b * DDIM * HDIM;
    } else {                       // enc: 4b x 8m(h) x 8n(e)
        int t2 = id - 64;
        int b = t2 >> 6, r = t2 & 63;
        m0 = (r >> 3) * 64; n0 = (r & 7) * 64;
        Ab = W1;
        Bb = xenc + (long)b * EDIM * HDIM;
        Cb = Q + (long)b * HDIM * EDIM;
    }

    const int t    = threadIdx.x;
    const int srow = t >> 2;            // 0..63: staged row
    const int skq  = (t & 3) << 3;      // 0,8,16,24: k-offset (8 elems)

    const int wid = t >> 6, wm = wid >> 1, wn = wid & 1;
    const int l   = t & 63, lr = l & 15, c16 = l >> 4;

    f32x4 acc[2][2] = {};

    const float* ap = Ab + (long)(m0 + srow) * HDIM + skq;
    const float* bp = Bb + (long)(n0 + srow) * HDIM + skq;

    float4 a0 = *(const float4*)ap, a1 = *(const float4*)(ap + 4);
    float4 b0 = *(const float4*)bp, b1 = *(const float4*)(bp + 4);

    int cur = 0;
    for (int k0 = 0; k0 < HDIM; k0 += 32) {
        uint4 apk, bpk;
        apk.x = pack_bf2(a0.x, a0.y); apk.y = pack_bf2(a0.z, a0.w);
        apk.z = pack_bf2(a1.x, a1.y); apk.w = pack_bf2(a1.z, a1.w);
        bpk.x = pack_bf2(b0.x, b0.y); bpk.y = pack_bf2(b0.z, b0.w);
        bpk.z = pack_bf2(b1.x, b1.y); bpk.w = pack_bf2(b1.z, b1.w);
        *(uint4*)&As[cur][srow][skq] = apk;
        *(uint4*)&Bs[cur][srow][skq] = bpk;

        if (k0 + 32 < HDIM) {
            ap += 32; bp += 32;
            a0 = *(const float4*)ap; a1 = *(const float4*)(ap + 4);
            b0 = *(const float4*)bp; b1 = *(const float4*)(bp + 4);
        }

        asm volatile("s_waitcnt lgkmcnt(0)" ::: "memory");
        __builtin_amdgcn_s_barrier();
        __builtin_amdgcn_sched_barrier(0);

        short8v af[2], bf[2];
        #pragma unroll
        for (int fm = 0; fm < 2; ++fm)
            af[fm] = *(const short8v*)&As[cur][wm * 32 + fm * 16 + lr][c16 * 8];
        #pragma unroll
        for (int fn = 0; fn < 2; ++fn)
            bf[fn] = *(const short8v*)&Bs[cur][wn * 32 + fn * 16 + lr][c16 * 8];
        #pragma unroll
        for (int fm = 0; fm < 2; ++fm)
            #pragma unroll
            for (int fn = 0; fn < 2; ++fn)
                acc[fm][fn] = __builtin_amdgcn_mfma_f32_16x16x32_bf16(
                    af[fm], bf[fn], acc[fm][fn], 0, 0, 0);
        cur ^= 1;
    }

    const int crow = c16 << 2;
    #pragma unroll
    for (int fm = 0; fm < 2; ++fm)
        #pragma unroll
        for (int fn = 0; fn < 2; ++fn)
            #pragma unroll
            for (int r = 0; r < 4; ++r) {
                int rr = m0 + wm * 32 + fm * 16 + crow + r;
                int cc = n0 + wn * 32 + fn * 16 + lr;
                Cb[(long)rr * 512 + cc] = f2bf(EXP2F(TANH_SCALE * acc[fm][fn][r]));
            }
}

// ---------------------------------------------------------------------------
// MERGED attn + log_softmax — byte-identical to R13 (best measured: 30.7).
// 256 blocks (1/CU), 1024 threads = 128 e-quads(4e) x 8 h-groups(64h).
// val_e = sum_h (-2 v[h]) * rcp(1 + P[d,h]*Q[h,e]); 2h pair-combine via
// v_pk packed math (1 rcp per 2h); 8-way LDS reduce; in-block masked
// log_softmax (waves 0-7 own d0, 8-15 own d1).
// ---------------------------------------------------------------------------
__global__ __launch_bounds__(1024)
void attn_lsm(const unsigned short* __restrict__ P,    // (B,D,H) bf16 exp2
              const unsigned short* __restrict__ Q,    // (B,H,E) bf16 exp2
              const unsigned char* __restrict__ mask,  // (B,E)
              const float* __restrict__ vw,            // (H)
              float* __restrict__ out) {               // (B,D,E)
    const int g    = blockIdx.x;            // 0..255
    const int xcd  = g & 7;
    const int b    = xcd & 3;
    const int dp   = (g >> 3) + ((xcd >> 2) << 5);     // 0..63
    const int pair = b * 64 + dp;           // 0..255
    const int bd0  = pair * 2;
    const int t    = threadIdx.x;           // 0..1023
    const int eq   = t & 127;               // e-quad (4 e's each)
    const int hg   = t >> 7;                // h-subgroup 0..7 (64 h each)

    __shared__ f32x2 combo2[256][3];        // per h-pair {P0pr,P1pr,(a,b)} 6KB
    __shared__ float lds[8][128][9];        // padded reduce buffer (36.9KB)
    __shared__ float red[16];

    if (t < 256) {
        int h = t * 2;
        f32x2 p0, p1, vv;
        p0.x = bf2f(P[bd0 * HDIM + h]);       p0.y = bf2f(P[bd0 * HDIM + h + 1]);
        p1.x = bf2f(P[(bd0 + 1) * HDIM + h]); p1.y = bf2f(P[(bd0 + 1) * HDIM + h + 1]);
        vv.x = -2.0f * vw[h];                 vv.y = -2.0f * vw[h + 1];
        combo2[t][0] = p0; combo2[t][1] = p1; combo2[t][2] = vv;
    }
    __syncthreads();

    const unsigned short* qb = Q + b * HDIM * EDIM + (hg * 64) * EDIM + eq * 4;
    float a00 = 0.f, a01 = 0.f, a02 = 0.f, a03 = 0.f;
    float a10 = 0.f, a11 = 0.f, a12 = 0.f, a13 = 0.f;
    f32x2 ones; ones.x = 1.0f; ones.y = 1.0f;

    // one "set": e-pair x d-row x (h0,h1) -> 5 pk + 2 rcp + 2 fma
#define PAIR_SET(Pp, q0p, q1p, VV, accA, accB)                                  \
    {                                                                           \
        f32x2 xp, yp, den, tt, num;                                             \
        asm("v_pk_fma_f32 %0, %1, %2, %3 op_sel_hi:[0,1,1]"                     \
            : "=v"(xp) : "v"(Pp), "v"(q0p), "v"(ones));                         \
        asm("v_pk_fma_f32 %0, %1, %2, %3 op_sel:[1,0,0] op_sel_hi:[1,1,1]"      \
            : "=v"(yp) : "v"(Pp), "v"(q1p), "v"(ones));                         \
        asm("v_pk_mul_f32 %0, %1, %2" : "=v"(den) : "v"(xp), "v"(yp));          \
        asm("v_pk_mul_f32 %0, %1, %2 op_sel:[1,0] op_sel_hi:[1,1]"              \
            : "=v"(tt) : "v"(VV), "v"(xp));                                     \
        asm("v_pk_fma_f32 %0, %1, %2, %3 op_sel_hi:[0,1,1]"                     \
            : "=v"(num) : "v"(VV), "v"(yp), "v"(tt));                           \
        accA = fmaf(num.x, RCPF(den.x), accA);                                  \
        accB = fmaf(num.y, RCPF(den.y), accB);                                  \
    }

    #pragma unroll 4
    for (int ii = 0; ii < 32; ++ii) {       // 32 h-pairs = 64 h
        uint2 qv0 = *(const uint2*)(qb + (size_t)(2 * ii) * EDIM);
        uint2 qv1 = *(const uint2*)(qb + (size_t)(2 * ii + 1) * EDIM);
        f32x2 P0 = combo2[hg * 32 + ii][0];
        f32x2 P1 = combo2[hg * 32 + ii][1];
        f32x2 VV = combo2[hg * 32 + ii][2];
        f32x2 qA0, qB0, qA1, qB1;           // (e0,e1) and (e2,e3) per h
        qA0.x = __uint_as_float(qv0.x << 16);
        qA0.y = __uint_as_float(qv0.x & 0xffff0000u);
        qB0.x = __uint_as_float(qv0.y << 16);
        qB0.y = __uint_as_float(qv0.y & 0xffff0000u);
        qA1.x = __uint_as_float(qv1.x << 16);
        qA1.y = __uint_as_float(qv1.x & 0xffff0000u);
        qB1.x = __uint_as_float(qv1.y << 16);
        qB1.y = __uint_as_float(qv1.y & 0xffff0000u);

        PAIR_SET(P0, qA0, qA1, VV, a00, a01);
        PAIR_SET(P0, qB0, qB1, VV, a02, a03);
        PAIR_SET(P1, qA0, qA1, VV, a10, a11);
        PAIR_SET(P1, qB0, qB1, VV, a12, a13);
    }
#undef PAIR_SET

    float* myl = &lds[hg][eq][0];
    myl[0] = a00; myl[1] = a01; myl[2] = a02; myl[3] = a03;
    myl[4] = a10; myl[5] = a11; myl[6] = a12; myl[7] = a13;
    __syncthreads();

    // cross-subgroup reduce: thread t owns output position t = d*512 + e
    const int d = t >> 9, e = t & 511;
    const int j = d * 4 + (e & 3), eqi = e >> 2;
    float acc = ((lds[0][eqi][j] + lds[1][eqi][j]) +
                 (lds[2][eqi][j] + lds[3][eqi][j])) +
                ((lds[4][eqi][j] + lds[5][eqi][j]) +
                 (lds[6][eqi][j] + lds[7][eqi][j]));

    const bool mk = mask[b * EDIM + e];
    float val = mk ? -INFINITY : acc;

    // --- masked log_softmax: waves 0..7 = d0, waves 8..15 = d1 ---
    const int wv = t >> 6, lid = t & 63, dg8 = d * 8;

    float m = val;
    #pragma unroll
    for (int o = 32; o >= 1; o >>= 1) m = fmaxf(m, __shfl_xor(m, o));
    if (lid == 0) red[wv] = m;
    __syncthreads();
    m = red[dg8];
    #pragma unroll
    for (int i = 1; i < 8; ++i) m = fmaxf(m, red[dg8 + i]);
    __syncthreads();

    float s = __expf(val - m);
    #pragma unroll
    for (int o = 32; o >= 1; o >>= 1) s += __shfl_xor(s, o);
    if (lid == 0) red[wv] = s;
    __syncthreads();
    float tot = 0.f;
    #pragma unroll
    for (int i = 0; i < 8; ++i) tot += red[dg8 + i];

    out[(long)(bd0 + d) * EDIM + e] = val - m - __logf(tot);
}

// ---------------------------------------------------------------------------
extern "C" void kernel_launch(void* const* d_in, const int* in_sizes, int n_in,
                              void* d_out, int out_size, void* d_ws, size_t ws_size,
                              hipStream_t stream) {
    const float*         xdec = (const float*)d_in[0];         // (B,D,H)
    const float*         xenc = (const float*)d_in[1];         // (B,E,H)
    const unsigned char* mask = (const unsigned char*)d_in[2]; // (B,E)
    const float*         W1   = (const float*)d_in[3];         // (H,H)
    const float*         W2   = (const float*)d_in[4];         // (H,H)
    const float*         vw   = (const float*)d_in[5];         // (H)
    float*               out  = (float*)d_out;                 // (B,D,E)

    unsigned short* P = (unsigned short*)d_ws;                 // 262144 bf16 (512 KB)
    unsigned short* Q = P + 262144;                            // 1048576 bf16 (2 MB)

    gemm_both<<<320, 256, 0, stream>>>(xdec, W2, xenc, W1, P, Q);
    attn_lsm<<<256, 1024, 0, stream>>>(P, Q, mask, vw, out);
}